// Round 9
// baseline (303.358 us; speedup 1.0000x reference)
//
#include <hip/hip_runtime.h>
#include <hip/hip_bf16.h>

#define N_ATOMS 100000
#define N_PAIRS 2000000
#define N_EMB 30
#define N_DIST 100
#define N_HID 60

#define TE 64                       // edges per tile
#define NTILES (N_PAIRS / TE)       // 31250 exact
#define EBLOCKS 1024                // 4 blocks/CU resident

typedef short bf16x8 __attribute__((ext_vector_type(8)));
typedef float f32x4 __attribute__((ext_vector_type(4)));

__device__ __forceinline__ ushort f2bf(float f) {
    __hip_bfloat16 h = __float2bfloat16(f);
    return __builtin_bit_cast(ushort, h);
}
__device__ __forceinline__ float bf2f(ushort u) {
    __hip_bfloat16 h = __builtin_bit_cast(__hip_bfloat16, u);
    return __bfloat162float(h);
}
__device__ __forceinline__ float fast_tanh(float x) {
    float e = __expf(2.0f * x);
    return 1.0f - 2.0f / (e + 1.0f);
}

// raw barrier: LDS-visibility only (lgkmcnt), leaves global loads in flight
__device__ __forceinline__ void lds_barrier() {
    asm volatile("s_waitcnt lgkmcnt(0)" ::: "memory");
    __builtin_amdgcn_s_barrier();
    __builtin_amdgcn_sched_barrier(0);
}

// ---------------- Kernel A: per-atom hidden + output init ----------------
__global__ __launch_bounds__(256) void atom_kernel(
    const float* __restrict__ af, const float* __restrict__ W_cf,
    const float* __restrict__ W_fc, const float* __restrict__ b_cf,
    const float* __restrict__ b_df, float* __restrict__ ah_out,
    float* __restrict__ out)
{
    __shared__ __align__(16) float ah_lds[4][N_HID];
    const int wave = threadIdx.x >> 6;
    const int lane = threadIdx.x & 63;
    const int n = blockIdx.x * 4 + wave;

    float ahv = 0.f;
    if (lane < N_HID) {
        ahv = b_cf[lane];
        #pragma unroll
        for (int k = 0; k < N_EMB; ++k)
            ahv = fmaf(af[(size_t)n * N_EMB + k], W_cf[k * N_HID + lane], ahv);
        ah_out[(size_t)n * N_HID + lane] = ahv;
        ah_lds[wave][lane] = ahv * b_df[lane];
    }
    __syncthreads();
    if (lane < N_EMB) {
        float s = 0.f;
        #pragma unroll
        for (int h = 0; h < N_HID; ++h)
            s = fmaf(ah_lds[wave][h], W_fc[h * N_EMB + lane], s);
        out[(size_t)n * N_EMB + lane] =
            af[(size_t)n * N_EMB + lane] - fast_tanh(s);
    }
}

// ---------------- Kernel B: 4-blocks/CU single-A pipeline, raw barriers ----------------
__global__ __launch_bounds__(256, 4) void edge_kernel(
    const float* __restrict__ dist,
    const int* __restrict__ mi, const int* __restrict__ mj,
    const float* __restrict__ W_df, const float* __restrict__ W_fc,
    const float* __restrict__ b_df, const float* __restrict__ ah,
    float* out)
{
    __shared__ ushort A_lds[TE * 136];        // 17408 B (single buffer)
    __shared__ ushort T_lds[TE * 72];         // 9216 B
    __shared__ ushort S_lds[32 * 72];         // 4608 B  (S^T: [f][edge])
    __shared__ ushort WFC[4 * 64 * 8];        // 4096 B  (wave-shared wfc fragments)
    __shared__ int    mis[2][TE], mjs[2][TE]; // 1024 B
    __shared__ int    seg_lds[TE];            // 256 B
    __shared__ int    seg_atom[TE];           // 256 B
    // total 36864 B -> 4 blocks/CU

    const int tid = threadIdx.x;
    const int wv = tid >> 6, lane = tid & 63;
    const int l4 = lane >> 4, ln = lane & 15;
    const int h1 = wv * 16 + ln;              // stage-1 hid col for this lane

    // ---- W_df fragments, single bf16 (16 VGPR) ----
    bf16x8 wdf[4];                            // [ks]: k = ks*32 + l4*8 + i, n = h1
    #pragma unroll
    for (int ks = 0; ks < 4; ++ks) {
        #pragma unroll
        for (int i = 0; i < 8; ++i) {
            int k = ks * 32 + l4 * 8 + i;
            float f = (k < N_DIST && h1 < N_HID) ? W_df[k * N_HID + h1] : 0.f;
            wdf[ks][i] = (short)f2bf(f);
        }
    }
    // ---- W_fc fragments -> LDS table (lane-dependent only, wave 0 builds) ----
    if (wv == 0) {
        #pragma unroll
        for (int nf = 0; nf < 2; ++nf) {
            #pragma unroll
            for (int ks = 0; ks < 2; ++ks) {
                bf16x8 w;
                #pragma unroll
                for (int i = 0; i < 8; ++i) {
                    int k = ks * 32 + l4 * 8 + i;
                    int n = nf * 16 + ln;
                    float f = (k < N_HID && n < N_EMB) ? W_fc[k * N_EMB + n] : 0.f;
                    w[i] = (short)f2bf(f);
                }
                *(bf16x8*)&WFC[(nf * 2 + ks) * 512 + lane * 8] = w;
            }
        }
    }
    const float bdf1 = (h1 < N_HID) ? b_df[h1] : 0.f;

    // zero A pad columns [100..136) once (never rewritten)
    for (int idx = tid; idx < TE * 36; idx += 256) {
        int r = idx / 36, c = 100 + idx % 36;
        A_lds[r * 136 + c] = 0;
    }

    const int t0 = (int)(((long long)blockIdx.x * NTILES) / EBLOCKS);
    const int t1 = (int)(((long long)(blockIdx.x + 1) * NTILES) / EBLOCKS);

    f32x4 pfa[3], pfb[4];
    int pmi = 0, pmj = 0;

    auto issue_a = [&](int t) {
        const f32x4* src = (const f32x4*)(dist + (size_t)t * TE * N_DIST);
        #pragma unroll
        for (int k = 0; k < 3; ++k)
            pfa[k] = __builtin_nontemporal_load(&src[k * 256 + tid]);
        if (tid < 64) {
            pmi = mi[t * TE + tid];
            pmj = mj[t * TE + tid];
        }
    };
    auto issue_b = [&](int t) {
        const f32x4* src = (const f32x4*)(dist + (size_t)t * TE * N_DIST);
        #pragma unroll
        for (int k = 0; k < 4; ++k)
            if (k < 3 || tid < 64)
                pfb[k] = __builtin_nontemporal_load(&src[(k + 3) * 256 + tid]);
    };
    auto write_a = [&](int buf) {
        #pragma unroll
        for (int k = 0; k < 3; ++k) {
            int idx = k * 256 + tid;
            int r = idx / 25, c = idx % 25;
            f32x4 v = pfa[k];
            ushort4 pk2;
            pk2.x = f2bf(v[0]); pk2.y = f2bf(v[1]);
            pk2.z = f2bf(v[2]); pk2.w = f2bf(v[3]);
            *(ushort4*)&A_lds[r * 136 + c * 4] = pk2;
        }
        if (tid < 64) { mis[buf][tid] = pmi; mjs[buf][tid] = pmj; }
    };
    auto write_b = [&]() {
        #pragma unroll
        for (int k = 0; k < 4; ++k) {
            if (k < 3 || tid < 64) {
                int idx = (k + 3) * 256 + tid;
                int r = idx / 25, c = idx % 25;
                f32x4 v = pfb[k];
                ushort4 pk2;
                pk2.x = f2bf(v[0]); pk2.y = f2bf(v[1]);
                pk2.z = f2bf(v[2]); pk2.w = f2bf(v[3]);
                *(ushort4*)&A_lds[r * 136 + c * 4] = pk2;
            }
        }
    };

    // prologue: stage tile t0 (full sync barrier once)
    issue_a(t0);
    issue_b(t0);
    write_a(0);
    write_b();
    __syncthreads();

    int cur = 0;
    for (int t = t0; t < t1; ++t) {
        const bool hasnext = (t + 1 < t1);

        // ---- gather ah (this tile) + issue next dist (survives raw barriers) ----
        float ahg[4][4];
        #pragma unroll
        for (int m = 0; m < 4; ++m) {
            #pragma unroll
            for (int r = 0; r < 4; ++r) {
                int el = 16 * m + l4 * 4 + r;
                int j = mjs[cur][el];
                ahg[m][r] = (h1 < N_HID) ? ah[(size_t)j * N_HID + h1] : 0.f;
            }
        }
        if (hasnext) issue_a(t + 1);

        // ---- stage-1 MFMA: 64 edges x 16 hids ----
        f32x4 acc1[4] = {{0,0,0,0},{0,0,0,0},{0,0,0,0},{0,0,0,0}};
        #pragma unroll
        for (int ks = 0; ks < 4; ++ks) {
            #pragma unroll
            for (int m = 0; m < 4; ++m) {
                bf16x8 a = *(const bf16x8*)&A_lds[(16 * m + ln) * 136 + ks * 32 + l4 * 8];
                acc1[m] = __builtin_amdgcn_mfma_f32_16x16x32_bf16(a, wdf[ks], acc1[m], 0, 0, 0);
            }
        }

        // ---- t = (dh + b_df) * ah -> bf16 -> T_lds ----
        #pragma unroll
        for (int m = 0; m < 4; ++m) {
            #pragma unroll
            for (int r = 0; r < 4; ++r) {
                int row = 16 * m + l4 * 4 + r;
                float tv = (acc1[m][r] + bdf1) * ahg[m][r];
                T_lds[row * 72 + h1] = (h1 < N_HID) ? f2bf(tv) : (ushort)0;
            }
        }
        lds_barrier();   // B2: T visible; A readers done

        // ---- write next A (first part) + issue rest ----
        if (hasnext) { write_a(cur ^ 1); issue_b(t + 1); }

        // ---- stage-2 MFMA: 16 edges x 32 f (wfc frags from LDS table) ----
        f32x4 acc2[2] = {{0,0,0,0},{0,0,0,0}};
        #pragma unroll
        for (int ks = 0; ks < 2; ++ks) {
            bf16x8 a2 = *(const bf16x8*)&T_lds[(16 * wv + ln) * 72 + ks * 32 + l4 * 8];
            #pragma unroll
            for (int nf = 0; nf < 2; ++nf) {
                bf16x8 w = *(const bf16x8*)&WFC[(nf * 2 + ks) * 512 + lane * 8];
                acc2[nf] = __builtin_amdgcn_mfma_f32_16x16x32_bf16(a2, w, acc2[nf], 0, 0, 0);
            }
        }
        // tanh -> S^T (bf16); rows f>=30 exact zeros
        #pragma unroll
        for (int nf = 0; nf < 2; ++nf) {
            #pragma unroll
            for (int r = 0; r < 4; ++r) {
                int f = nf * 16 + ln;
                int e = 16 * wv + l4 * 4 + r;
                S_lds[f * 72 + e] = f2bf(fast_tanh(acc2[nf][r]));
            }
        }
        if (hasnext) write_b();

        lds_barrier();   // B3: S + next-A + metadata visible

        // ---- per-tile segment metadata (redundant per wave, identical) ----
        int m_e = mis[cur][lane];
        int prevv = __shfl_up(m_e, 1);
        bool changed = (lane > 0) && (m_e != prevv);
        unsigned long long bmask = __ballot(changed);
        int segl = __popcll(bmask & ((2ull << lane) - 1ull));
        if (lane == 0 || changed) seg_atom[segl] = m_e;
        seg_lds[lane] = segl;
        int nseg = __popcll(bmask) + 1;

        // ---- selector MFMA: C[seg][f] = sel[seg][e] @ S[e][f] ----
        int myseg = 16 * wv + ln;
        f32x4 acc3[2] = {{0,0,0,0},{0,0,0,0}};
        #pragma unroll
        for (int ks = 0; ks < 2; ++ks) {
            bf16x8 sfr;
            const int* sp = &seg_lds[ks * 32 + l4 * 8];
            #pragma unroll
            for (int i = 0; i < 8; ++i)
                sfr[i] = (sp[i] == myseg) ? (short)0x3F80 : (short)0;
            #pragma unroll
            for (int nf = 0; nf < 2; ++nf) {
                bf16x8 b = *(const bf16x8*)&S_lds[(nf * 16 + ln) * 72 + ks * 32 + l4 * 8];
                acc3[nf] = __builtin_amdgcn_mfma_f32_16x16x32_bf16(sfr, b, acc3[nf], 0, 0, 0);
            }
        }
        // ---- flush: one atomicAdd per (present segment, f) ----
        #pragma unroll
        for (int nf = 0; nf < 2; ++nf) {
            #pragma unroll
            for (int r = 0; r < 4; ++r) {
                int gs = 16 * wv + l4 * 4 + r;
                int f = nf * 16 + ln;
                if (gs < nseg && f < N_EMB) {
                    int atomId = seg_atom[gs];
                    atomicAdd(&out[(size_t)atomId * N_EMB + f], acc3[nf][r]);
                }
            }
        }
        cur ^= 1;
    }
}

extern "C" void kernel_launch(void* const* d_in, const int* in_sizes, int n_in,
                              void* d_out, int out_size, void* d_ws, size_t ws_size,
                              hipStream_t stream) {
    const float* af   = (const float*)d_in[0];
    const float* dist = (const float*)d_in[1];
    const int*   mi   = (const int*)d_in[2];
    const int*   mj   = (const int*)d_in[3];
    const float* W_cf = (const float*)d_in[4];
    const float* W_df = (const float*)d_in[5];
    const float* W_fc = (const float*)d_in[6];
    const float* b_cf = (const float*)d_in[7];
    const float* b_df = (const float*)d_in[8];
    float* out = (float*)d_out;
    float* ah  = (float*)d_ws;   // N_ATOMS * N_HID floats = 24 MB

    atom_kernel<<<N_ATOMS / 4, 256, 0, stream>>>(af, W_cf, W_fc, b_cf, b_df, ah, out);
    edge_kernel<<<EBLOCKS, 256, 0, stream>>>(dist, mi, mj, W_df, W_fc, b_df, ah, out);
}